// Round 4
// baseline (224.731 us; speedup 1.0000x reference)
//
#include <hip/hip_runtime.h>
#include <math.h>

// Problem constants (from reference): B=64, D=128, N=500000, K+1=4096
constexpr int Bb   = 64;
constexpr int Dd   = 128;
constexpr int KP1  = 4096;
constexpr long NMEM = 500000L * 128;   // elements per memory bank
constexpr int BK   = Bb * KP1;         // 262144 elements per score output

constexpr int SPLIT = 4;               // score blocks per (b,which)
constexpr int CSEG  = KP1 / SPLIT;     // 1024 candidates per score block
constexpr int NSCORE = Bb * 2 * SPLIT; // 512 score blocks

// native clang vector type (usable with __builtin_nontemporal_store)
typedef float f4 __attribute__((ext_vector_type(4)));

// Output layout (flat, reference return order):
// [0, BK)                 out_image
// [BK, 2*BK)              out_gene
// [2*BK, 2*BK+NMEM)       new_memory_image
// [2*BK+NMEM, 2*BK+2NMEM) new_memory_gene

__device__ __forceinline__ float dot8(float4 a, float4 b, float4 x0, float4 x1) {
    return a.x*x0.x + a.y*x0.y + a.z*x0.z + a.w*x0.w
         + b.x*x1.x + b.y*x1.y + b.z*x1.z + b.w*x1.w;
}

// Fused kernel:
//  blocks [0, NSCORE): partial scores + partial softmax.
//    sb = blockIdx.x; seg = sb&3, which = (sb>>2)&1, b = sb>>3.
//    Writes unnormalized exp(s - m_local) to out, (m_local, sum_local) to ws.
//  blocks [NSCORE, NSCORE+nCopy): streaming bank copy, bank = (blk-NSCORE)&1.
__global__ __launch_bounds__(512) void fused_scores_copy(
    const float* __restrict__ image, const float* __restrict__ gene,
    const float* __restrict__ mem_image, const float* __restrict__ mem_gene,
    const int* __restrict__ idx, float* __restrict__ out,
    float2* __restrict__ ws, int nCopyBlocks)
{
    const int tid = threadIdx.x;

    if (blockIdx.x >= NSCORE) {
        // ---- streaming copy, one bank per block ----
        const long half = NMEM / 4;               // float4 per bank (16M)
        const int  cb   = blockIdx.x - NSCORE;
        const int  bank = cb & 1;                 // 0 -> image, 1 -> gene
        const f4* src = bank ? (const f4*)mem_gene : (const f4*)mem_image;
        f4* dst = (f4*)(out + 2 * BK) + (long)bank * half;
        const long stride = (long)(nCopyBlocks >> 1) * 512;
        long i = (long)(cb >> 1) * 512 + tid;
        // 8x unrolled: 8 independent loads in flight per thread
        for (; i + 7 * stride < half; i += 8 * stride) {
            f4 v0 = src[i];
            f4 v1 = src[i + stride];
            f4 v2 = src[i + 2 * stride];
            f4 v3 = src[i + 3 * stride];
            f4 v4 = src[i + 4 * stride];
            f4 v5 = src[i + 5 * stride];
            f4 v6 = src[i + 6 * stride];
            f4 v7 = src[i + 7 * stride];
            __builtin_nontemporal_store(v0, dst + i);
            __builtin_nontemporal_store(v1, dst + i + stride);
            __builtin_nontemporal_store(v2, dst + i + 2 * stride);
            __builtin_nontemporal_store(v3, dst + i + 3 * stride);
            __builtin_nontemporal_store(v4, dst + i + 4 * stride);
            __builtin_nontemporal_store(v5, dst + i + 5 * stride);
            __builtin_nontemporal_store(v6, dst + i + 6 * stride);
            __builtin_nontemporal_store(v7, dst + i + 7 * stride);
        }
        for (; i < half; i += stride)
            __builtin_nontemporal_store(src[i], dst + i);
        return;
    }

    // ---- partial scores + partial softmax over CSEG candidates ----
    const int sb    = blockIdx.x;
    const int seg   = sb & (SPLIT - 1);
    const int which = (sb >> 2) & 1;
    const int b     = sb >> 3;
    const float* w = which ? mem_image : mem_gene;
    const float* x = which ? gene : image;
    float* o = out + (long)which * BK + (long)b * KP1 + seg * CSEG;

    __shared__ int   sidx[CSEG];   // 4 KB
    __shared__ float sv[CSEG];     // 4 KB
    __shared__ float red[8];

    // vectorized idx preload: 1024 ints = 256 int4
    if (tid < 256) {
        const int4* s4 = (const int4*)(idx + (long)b * KP1 + seg * CSEG);
        ((int4*)sidx)[tid] = s4[tid];
    }

    const int lg  = tid & 15;      // lane within 16-lane group (one 512B row)
    const int grp = tid >> 4;      // 0..31 groups

    float4 x0 = *(const float4*)(x + b * Dd + lg * 8);
    float4 x1 = *(const float4*)(x + b * Dd + lg * 8 + 4);
    __syncthreads();

    // gather + dot: 32 candidates per group, 4x unrolled (8 f4 loads in flight)
    for (int j = 0; j < 32; j += 4) {
        const int k0 = grp + (j + 0) * 32;
        const int k1 = grp + (j + 1) * 32;
        const int k2 = grp + (j + 2) * 32;
        const int k3 = grp + (j + 3) * 32;
        const float4* r0 = (const float4*)(w + (long)sidx[k0] * Dd + lg * 8);
        const float4* r1 = (const float4*)(w + (long)sidx[k1] * Dd + lg * 8);
        const float4* r2 = (const float4*)(w + (long)sidx[k2] * Dd + lg * 8);
        const float4* r3 = (const float4*)(w + (long)sidx[k3] * Dd + lg * 8);
        float4 a0 = r0[0], b0 = r0[1];
        float4 a1 = r1[0], b1 = r1[1];
        float4 a2 = r2[0], b2 = r2[1];
        float4 a3 = r3[0], b3 = r3[1];
        float d0 = dot8(a0, b0, x0, x1);
        float d1 = dot8(a1, b1, x0, x1);
        float d2 = dot8(a2, b2, x0, x1);
        float d3 = dot8(a3, b3, x0, x1);
        d0 += __shfl_xor(d0, 1); d1 += __shfl_xor(d1, 1);
        d2 += __shfl_xor(d2, 1); d3 += __shfl_xor(d3, 1);
        d0 += __shfl_xor(d0, 2); d1 += __shfl_xor(d1, 2);
        d2 += __shfl_xor(d2, 2); d3 += __shfl_xor(d3, 2);
        d0 += __shfl_xor(d0, 4); d1 += __shfl_xor(d1, 4);
        d2 += __shfl_xor(d2, 4); d3 += __shfl_xor(d3, 4);
        d0 += __shfl_xor(d0, 8); d1 += __shfl_xor(d1, 8);
        d2 += __shfl_xor(d2, 8); d3 += __shfl_xor(d3, 8);
        if (lg == 0) {
            sv[k0] = d0; sv[k1] = d1; sv[k2] = d2; sv[k3] = d3;
        }
    }
    __syncthreads();

    // local max over CSEG (each thread: 2 elems)
    float m = fmaxf(sv[tid], sv[tid + 512]);
    #pragma unroll
    for (int off = 1; off < 64; off <<= 1) m = fmaxf(m, __shfl_xor(m, off));
    if ((tid & 63) == 0) red[tid >> 6] = m;
    __syncthreads();
    if (tid < 64) {
        float tv = (tid < 8) ? red[tid] : -INFINITY;
        #pragma unroll
        for (int off = 1; off < 8; off <<= 1) tv = fmaxf(tv, __shfl_xor(tv, off));
        if (tid == 0) red[0] = tv;
    }
    __syncthreads();
    m = red[0];
    __syncthreads();   // red about to be reused

    // exp + local sum; write unnormalized exp to out
    float e0 = expf(sv[tid] - m);
    float e1 = expf(sv[tid + 512] - m);
    o[tid]       = e0;
    o[tid + 512] = e1;
    float sum = e0 + e1;
    #pragma unroll
    for (int off = 1; off < 64; off <<= 1) sum += __shfl_xor(sum, off);
    if ((tid & 63) == 0) red[tid >> 6] = sum;
    __syncthreads();
    if (tid < 64) {
        float tv = (tid < 8) ? red[tid] : 0.f;
        #pragma unroll
        for (int off = 1; off < 8; off <<= 1) tv += __shfl_xor(tv, off);
        if (tid == 0) ws[((which * Bb + b) << 2) | seg] = make_float2(m, tv);
    }
}

// Epilogue: blocks [0,128) softmax-rescale; blocks [128,160) momentum update.
__global__ __launch_bounds__(512) void epilogue(
    const float* __restrict__ image, const float* __restrict__ gene,
    const float* __restrict__ mem_image, const float* __restrict__ mem_gene,
    const int* __restrict__ index, const float2* __restrict__ ws,
    float* __restrict__ out)
{
    const int tid = threadIdx.x;

    if (blockIdx.x < 128) {
        // ---- rescale partial softmax segments into final softmax ----
        const int which = blockIdx.x & 1;
        const int b     = blockIdx.x >> 1;
        const float2* p = ws + ((which * Bb + b) << 2);
        float2 p0 = p[0], p1 = p[1], p2 = p[2], p3 = p[3];
        float M = fmaxf(fmaxf(p0.x, p1.x), fmaxf(p2.x, p3.x));
        float s0 = expf(p0.x - M), s1 = expf(p1.x - M);
        float s2 = expf(p2.x - M), s3 = expf(p3.x - M);
        float denom = p0.y * s0 + p1.y * s1 + p2.y * s2 + p3.y * s3;
        const float inv = 1.0f / denom;
        float scale[SPLIT] = { s0 * inv, s1 * inv, s2 * inv, s3 * inv };
        float* o = out + (long)which * BK + (long)b * KP1;
        #pragma unroll
        for (int r = 0; r < 8; ++r) {
            int k = tid + r * 512;
            o[k] *= scale[k >> 10];
        }
        return;
    }

    // ---- momentum update: 32 blocks x 4 tasks (task = 128 threads) ----
    const int task  = ((blockIdx.x - 128) << 2) | (tid >> 7);  // 0..127
    const int sub   = tid >> 7;        // 0..3
    const int d     = tid & 127;
    const int which = task >> 6;       // 0 -> image bank, 1 -> gene bank
    const int b     = task & 63;
    const float* mem = which ? mem_gene : mem_image;
    const float* x   = which ? gene : image;
    float* o = out + 2 * BK + (long)which * NMEM;

    const long row = index[b];
    float p = mem[row * Dd + d] * 0.5f + x[(long)b * Dd + d] * 0.5f;
    float ss = p * p;
    #pragma unroll
    for (int off = 1; off < 64; off <<= 1) ss += __shfl_xor(ss, off);
    __shared__ float r2[8];            // one per wave
    if ((tid & 63) == 0) r2[tid >> 6] = ss;
    __syncthreads();
    const float inv = 1.0f / sqrtf(r2[2 * sub] + r2[2 * sub + 1]);
    o[row * Dd + d] = p * inv;
}

extern "C" void kernel_launch(void* const* d_in, const int* in_sizes, int n_in,
                              void* d_out, int out_size, void* d_ws, size_t ws_size,
                              hipStream_t stream) {
    const float* image     = (const float*)d_in[0];
    const float* gene      = (const float*)d_in[1];
    const float* mem_image = (const float*)d_in[2];
    const float* mem_gene  = (const float*)d_in[3];
    const int*   index     = (const int*)d_in[4];
    const int*   idx       = (const int*)d_in[5];
    float* out = (float*)d_out;
    float2* ws = (float2*)d_ws;

    const int nCopy = 1920;   // even: half image bank, half gene bank
    fused_scores_copy<<<dim3(NSCORE + nCopy), 512, 0, stream>>>(
        image, gene, mem_image, mem_gene, idx, out, ws, nCopy);
    epilogue<<<dim3(160), 512, 0, stream>>>(
        image, gene, mem_image, mem_gene, index, ws, out);
}

// Round 6
// 215.590 us; speedup vs baseline: 1.0424x; 1.0424x over previous
//
#include <hip/hip_runtime.h>
#include <math.h>

// Problem constants (from reference): B=64, D=128, N=500000, K+1=4096
constexpr int Bb   = 64;
constexpr int Dd   = 128;
constexpr int KP1  = 4096;
constexpr long NMEM = 500000L * 128;   // elements per memory bank
constexpr int BK   = Bb * KP1;         // 262144 elements per score output

// copy chunking: each bank = NMEM/4 = 16,000,000 f4 (NOT a power of two).
// 1953 full chunks of 8192 f4 (= 15,998,976) + one tail chunk of 1024 f4.
constexpr long HALF_F4    = NMEM / 4;        // 16,000,000
constexpr int  CHUNK_F4   = 8192;            // 128 KB
constexpr int  FULL_PER_B = 1953;            // full chunks per bank
constexpr long TAIL_BASE  = (long)FULL_PER_B * CHUNK_F4;  // 15,998,976
constexpr int  TAIL_F4    = (int)(HALF_F4 - TAIL_BASE);   // 1024
constexpr int  CHUNKS_PER_BANK = FULL_PER_B + 1;          // 1954
constexpr int  NCHUNK     = 2 * CHUNKS_PER_BANK;          // 3908

// native clang vector type (usable with __builtin_nontemporal_store)
typedef float f4 __attribute__((ext_vector_type(4)));

// Output layout (flat, reference return order):
// [0, BK)                 out_image
// [BK, 2*BK)              out_gene
// [2*BK, 2*BK+NMEM)       new_memory_image
// [2*BK+NMEM, 2*BK+2NMEM) new_memory_gene

__device__ __forceinline__ float dot8(float4 a, float4 b, float4 x0, float4 x1) {
    return a.x*x0.x + a.y*x0.y + a.z*x0.z + a.w*x0.w
         + b.x*x1.x + b.y*x1.y + b.z*x1.z + b.w*x1.w;
}

// Zero the work-steal counter (must run before fused, every launch).
__global__ __launch_bounds__(64) void zero_ctr(unsigned* ctr) {
    if (threadIdx.x == 0) *ctr = 0u;
}

// Fused kernel, 2048 blocks x 512 threads:
//  blocks [0,128): full scores + exact softmax for (b = blk>>1, which = blk&1),
//    then fall through to the work-steal copy loop.
//  all blocks: work-steal 128KB copy chunks until exhausted.
__global__ __launch_bounds__(512, 2) void fused_scores_copy(
    const float* __restrict__ image, const float* __restrict__ gene,
    const float* __restrict__ mem_image, const float* __restrict__ mem_gene,
    const int* __restrict__ idx, float* __restrict__ out, unsigned* __restrict__ ctr)
{
    const int tid = threadIdx.x;

    if (blockIdx.x < 128) {
        // ---- scores + exact softmax (R3-proven path) ----
        const int b     = blockIdx.x >> 1;
        const int which = blockIdx.x & 1;
        const float* w = which ? mem_image : mem_gene;
        const float* x = which ? gene : image;
        float* o = out + (long)which * BK + (long)b * KP1;

        __shared__ int   sidx[KP1];   // 16 KB
        __shared__ float sv[KP1];     // 16 KB
        __shared__ float red[8];

        {   // vectorized idx preload: 4096 ints = 1024 int4
            const int4* s4 = (const int4*)(idx + (long)b * KP1);
            int4* d4 = (int4*)sidx;
            d4[tid]       = s4[tid];
            d4[tid + 512] = s4[tid + 512];
        }

        const int lg  = tid & 15;
        const int grp = tid >> 4;

        float4 x0 = *(const float4*)(x + b * Dd + lg * 8);
        float4 x1 = *(const float4*)(x + b * Dd + lg * 8 + 4);
        __syncthreads();

        for (int j = 0; j < 128; j += 4) {
            const int k0 = grp + (j + 0) * 32;
            const int k1 = grp + (j + 1) * 32;
            const int k2 = grp + (j + 2) * 32;
            const int k3 = grp + (j + 3) * 32;
            const float4* r0 = (const float4*)(w + (long)sidx[k0] * Dd + lg * 8);
            const float4* r1 = (const float4*)(w + (long)sidx[k1] * Dd + lg * 8);
            const float4* r2 = (const float4*)(w + (long)sidx[k2] * Dd + lg * 8);
            const float4* r3 = (const float4*)(w + (long)sidx[k3] * Dd + lg * 8);
            float4 a0 = r0[0], b0 = r0[1];
            float4 a1 = r1[0], b1 = r1[1];
            float4 a2 = r2[0], b2 = r2[1];
            float4 a3 = r3[0], b3 = r3[1];
            float d0 = dot8(a0, b0, x0, x1);
            float d1 = dot8(a1, b1, x0, x1);
            float d2 = dot8(a2, b2, x0, x1);
            float d3 = dot8(a3, b3, x0, x1);
            d0 += __shfl_xor(d0, 1); d1 += __shfl_xor(d1, 1);
            d2 += __shfl_xor(d2, 1); d3 += __shfl_xor(d3, 1);
            d0 += __shfl_xor(d0, 2); d1 += __shfl_xor(d1, 2);
            d2 += __shfl_xor(d2, 2); d3 += __shfl_xor(d3, 2);
            d0 += __shfl_xor(d0, 4); d1 += __shfl_xor(d1, 4);
            d2 += __shfl_xor(d2, 4); d3 += __shfl_xor(d3, 4);
            d0 += __shfl_xor(d0, 8); d1 += __shfl_xor(d1, 8);
            d2 += __shfl_xor(d2, 8); d3 += __shfl_xor(d3, 8);
            if (lg == 0) {
                sv[k0] = d0; sv[k1] = d1; sv[k2] = d2; sv[k3] = d3;
            }
        }
        __syncthreads();

        // block max
        float m = fmaxf(sv[tid], sv[tid + 512]);
        m = fmaxf(m, fmaxf(sv[tid + 1024], sv[tid + 1536]));
        m = fmaxf(m, fmaxf(sv[tid + 2048], sv[tid + 2560]));
        m = fmaxf(m, fmaxf(sv[tid + 3072], sv[tid + 3584]));
        #pragma unroll
        for (int off = 1; off < 64; off <<= 1) m = fmaxf(m, __shfl_xor(m, off));
        if ((tid & 63) == 0) red[tid >> 6] = m;
        __syncthreads();
        if (tid < 64) {
            float tv = (tid < 8) ? red[tid] : -INFINITY;
            #pragma unroll
            for (int off = 1; off < 8; off <<= 1) tv = fmaxf(tv, __shfl_xor(tv, off));
            if (tid == 0) red[0] = tv;
        }
        __syncthreads();
        m = red[0];
        __syncthreads();   // red about to be reused

        // exp + block sum
        float sum = 0.f;
        #pragma unroll
        for (int r = 0; r < 8; ++r) {
            int k = tid + r * 512;
            float e = expf(sv[k] - m);
            sv[k] = e;
            sum += e;
        }
        #pragma unroll
        for (int off = 1; off < 64; off <<= 1) sum += __shfl_xor(sum, off);
        if ((tid & 63) == 0) red[tid >> 6] = sum;
        __syncthreads();
        if (tid < 64) {
            float tv = (tid < 8) ? red[tid] : 0.f;
            #pragma unroll
            for (int off = 1; off < 8; off <<= 1) tv += __shfl_xor(tv, off);
            if (tid == 0) red[0] = tv;
        }
        __syncthreads();
        const float inv = 1.0f / red[0];
        #pragma unroll
        for (int r = 0; r < 8; ++r) {
            int k = tid + r * 512;
            o[k] = sv[k] * inv;
        }
        // fall through: join the copy
    }

    // ---- work-steal streaming copy ----
    const f4* srcI = (const f4*)mem_image;
    const f4* srcG = (const f4*)mem_gene;
    f4* dst = (f4*)(out + 2 * BK);          // banks contiguous in out

    __shared__ unsigned sc;
    for (;;) {
        if (tid == 0) sc = atomicAdd(ctr, 1u);
        __syncthreads();
        const unsigned c = sc;
        __syncthreads();                    // sc reused next iteration
        if (c >= NCHUNK) break;

        const int  bank  = (c < CHUNKS_PER_BANK) ? 0 : 1;
        const int  local = bank ? (int)(c - CHUNKS_PER_BANK) : (int)c;
        const f4*  sbank = bank ? srcG : srcI;
        const long dbank = (long)bank * HALF_F4;

        if (local < FULL_PER_B) {
            const long base = (long)local * CHUNK_F4;
            f4 v[16];
            #pragma unroll
            for (int k = 0; k < 16; ++k) v[k] = sbank[base + k * 512 + tid];
            #pragma unroll
            for (int k = 0; k < 16; ++k)
                __builtin_nontemporal_store(v[k], dst + dbank + base + k * 512 + tid);
        } else {
            // tail: 1024 f4, 2 per thread
            f4 v0 = sbank[TAIL_BASE + tid];
            f4 v1 = sbank[TAIL_BASE + 512 + tid];
            __builtin_nontemporal_store(v0, dst + dbank + TAIL_BASE + tid);
            __builtin_nontemporal_store(v1, dst + dbank + TAIL_BASE + 512 + tid);
        }
    }
}

// Momentum scatter-update of the 64 rows per bank, AFTER the copy (stream order).
__global__ __launch_bounds__(128) void momentum_update(
    const float* __restrict__ image, const float* __restrict__ gene,
    const float* __restrict__ mem_image, const float* __restrict__ mem_gene,
    const int* __restrict__ index, float* __restrict__ out)
{
    const int b     = blockIdx.x;
    const int which = blockIdx.y;   // 0 -> image bank, 1 -> gene bank
    const float* mem = which ? mem_gene : mem_image;
    const float* x   = which ? gene : image;
    float* o = out + 2 * BK + (long)which * NMEM;

    const long row = index[b];
    const int d = threadIdx.x;   // 0..127

    float p = mem[row * Dd + d] * 0.5f + x[(long)b * Dd + d] * 0.5f;
    float ss = p * p;
    #pragma unroll
    for (int off = 1; off < 64; off <<= 1) ss += __shfl_xor(ss, off);
    __shared__ float r2[2];
    if ((d & 63) == 0) r2[d >> 6] = ss;
    __syncthreads();
    const float inv = 1.0f / sqrtf(r2[0] + r2[1]);
    o[row * Dd + d] = p * inv;
}

extern "C" void kernel_launch(void* const* d_in, const int* in_sizes, int n_in,
                              void* d_out, int out_size, void* d_ws, size_t ws_size,
                              hipStream_t stream) {
    const float* image     = (const float*)d_in[0];
    const float* gene      = (const float*)d_in[1];
    const float* mem_image = (const float*)d_in[2];
    const float* mem_gene  = (const float*)d_in[3];
    const int*   index     = (const int*)d_in[4];
    const int*   idx       = (const int*)d_in[5];
    float* out = (float*)d_out;
    unsigned* ctr = (unsigned*)d_ws;

    zero_ctr<<<dim3(1), 64, 0, stream>>>(ctr);
    fused_scores_copy<<<dim3(2048), 512, 0, stream>>>(
        image, gene, mem_image, mem_gene, idx, out, ctr);
    momentum_update<<<dim3(64, 2), 128, 0, stream>>>(
        image, gene, mem_image, mem_gene, index, out);
}